// Round 14
// baseline (1241.775 us; speedup 1.0000x reference)
//
#include <hip/hip_runtime.h>
#include <hip/hip_bf16.h>

#define N_COARSE 12500
#define N_FINE   50000

typedef __bf16 bf16x8 __attribute__((ext_vector_type(8)));
typedef __bf16 bf16x4 __attribute__((ext_vector_type(4)));
typedef float  f32x4  __attribute__((ext_vector_type(4)));

// ---------------------------------------------------------------------------
// Fragment conventions (v_mfma_f32_16x16x32_bf16), HW-verified:
//   a-frag: lane holds A[row = lane&15][k = (lane>>4)*8 + j]
//   b-frag: lane holds B[k = (lane>>4)*8 + j][col = lane&15]
//   d     : lane holds D[row = (lane>>4)*4 + j][col = lane&15]
// ---------------------------------------------------------------------------

__device__ __forceinline__ bf16x8 cvt8(f32x4 x, f32x4 y) {
    bf16x8 r;
    r[0] = (__bf16)x[0]; r[1] = (__bf16)x[1]; r[2] = (__bf16)x[2]; r[3] = (__bf16)x[3];
    r[4] = (__bf16)y[0]; r[5] = (__bf16)y[1]; r[6] = (__bf16)y[2]; r[7] = (__bf16)y[3];
    return r;
}

// Barrier with LDS-only fence (avoids __syncthreads' vmcnt(0) drain).
__device__ __forceinline__ void lds_barrier() {
    asm volatile("s_waitcnt lgkmcnt(0)" ::: "memory");
    __builtin_amdgcn_s_barrier();
}

// ---- LDS A-tile: [64 rows][256 bf16] = 32 KB, XOR-swizzled ----------------
__device__ __forceinline__ int swz(int row, int byte) { return byte ^ ((row & 7) << 4); }
__device__ __forceinline__ void st_a(__bf16* lds, int row, int cs, bf16x8 v) {
    *(bf16x8*)((char*)lds + swz(row, row * 512 + cs * 16)) = v;
}
__device__ __forceinline__ bf16x8 ld_a(const __bf16* lds, int row, int ka) {
    return *(const bf16x8*)((const char*)lds + swz(row, row * 512 + ka * 2));
}

template<int NT>
__device__ __forceinline__ void stage_f32(const float* __restrict__ A, long row0,
                                          __bf16* lds, int tid, long maxrow) {
    const int r0 = tid >> 5, cs = tid & 31;
    constexpr int RPI = NT / 32;
    #pragma unroll
    for (int i = 0; i < 64 / RPI; ++i) {
        int row = r0 + i * RPI;
        long gr = row0 + row; if (gr > maxrow) gr = maxrow;
        const float* p = A + gr * 256 + cs * 8;
        f32x4 x = *(const f32x4*)p, y = *(const f32x4*)(p + 4);
        st_a(lds, row, cs, cvt8(x, y));
    }
}

// 64x64-per-wave MFMA over one 256-wide K segment, A from LDS, B packed global
__device__ __forceinline__ void mfma_tile(const __bf16* lds, const bf16x8* __restrict__ packB,
                                          int N, int c0, int ksb,
                                          f32x4 (&acc)[4][4], int lane) {
    const int g = lane >> 4, r15 = lane & 15;
    #pragma unroll
    for (int ks = 0; ks < 8; ++ks) {
        bf16x8 a[4];
        #pragma unroll
        for (int rt = 0; rt < 4; ++rt)
            a[rt] = ld_a(lds, rt * 16 + r15, ks * 32 + g * 8);
        const size_t kb = (size_t)((ksb + ks) * 4 + g) * N;
        #pragma unroll
        for (int ct = 0; ct < 4; ++ct) {
            bf16x8 b = packB[kb + c0 + ct * 16 + r15];
            #pragma unroll
            for (int rt = 0; rt < 4; ++rt)
                acc[rt][ct] = __builtin_amdgcn_mfma_f32_16x16x32_bf16(a[rt], b, acc[rt][ct], 0, 0, 0);
        }
    }
}

// ---------------------------------------------------------------------------
// Merged prep: pack W_le / W_ce / W_mlp into MFMA b-frag layout + cvt last_inv
// to bf16. Pack layout: dst[((k>>3)*N + n)*8 + (k&7)] = (bf16)W[k*N + n]
// ---------------------------------------------------------------------------
__global__ __launch_bounds__(256) void k_prep(
    const float* __restrict__ W_le, const float* __restrict__ W_ce,
    const float* __restrict__ W_mlp, const float* __restrict__ last_inv,
    __bf16* __restrict__ packLE, __bf16* __restrict__ packCE,
    __bf16* __restrict__ packM, __bf16* __restrict__ li_bf)
{
    const int b = blockIdx.x, tid = threadIdx.x;
    if (b < 256) {                       // W_le pack (256x256)
        int idx = b * 256 + tid, k = idx >> 8, n = idx & 255;
        packLE[(((size_t)(k >> 3) << 8) + n) * 8 + (k & 7)] = (__bf16)W_le[idx];
    } else if (b < 512) {                // W_ce pack (256x256)
        int idx = (b - 256) * 256 + tid, k = idx >> 8, n = idx & 255;
        packCE[(((size_t)(k >> 3) << 8) + n) * 8 + (k & 7)] = (__bf16)W_ce[idx];
    } else if (b < 2048) {               // W_mlp pack (768x512)
        int idx = (b - 512) * 256 + tid, k = idx >> 9, n = idx & 511;
        packM[(((size_t)(k >> 3) << 9) + n) * 8 + (k & 7)] = (__bf16)W_mlp[idx];
    } else {                             // last_inv f32 -> bf16
        int i = (b - 2048) * 256 + tid;
        f32x4 v = ((const f32x4*)last_inv)[i];
        bf16x4 o;
        o[0] = (__bf16)v[0]; o[1] = (__bf16)v[1]; o[2] = (__bf16)v[2]; o[3] = (__bf16)v[3];
        ((bf16x4*)li_bf)[i] = o;
    }
}

// ---------------------------------------------------------------------------
// Fine FULLY-fused (coarse folded in): per 4-point tile,
//   stage last_equ[parents] (64 gathered rows) -> MFMA packLE -> LE acc
//   (D-layout matches CE's point<->parent sub-tile mapping exactly)
//   -> cvt LE acc to bf16 le[][] in-register (bit-identical to old LEp path)
//   -> stage cur_equ -> MFMA packCE -> product -> basis-mean -> equ.
// No LEp buffer, no coarse kernel, no gather. last_equ (204.8 MB) fits L3,
// so the ~4x logical reuse across fine points is L3-served.
// PERSISTENT grid-stride (R13's proven convoy fix).
// ---------------------------------------------------------------------------
__global__ __launch_bounds__(256) void k_fine_equ(
    const float* __restrict__ last_equ, const float* __restrict__ cur_equ,
    const bf16x8* __restrict__ packLE, const bf16x8* __restrict__ packCE,
    const int* __restrict__ up, __bf16* __restrict__ equ)
{
    __shared__ __attribute__((aligned(16))) __bf16 As[64 * 256];
    const int tid = threadIdx.x, lane = tid & 63, wid = tid >> 6;
    const int r0 = tid >> 5, cs = tid & 31;

    for (int t = blockIdx.x; t < N_FINE / 4; t += gridDim.x) {
        const int n0 = t * 4;
        int cu[4];
        #pragma unroll
        for (int rt = 0; rt < 4; ++rt) cu[rt] = up[n0 + rt];   // uniform -> s_load

        // ---- stage last_equ rows of the 4 parents (coalesced per row) ----
        #pragma unroll
        for (int i = 0; i < 8; ++i) {                 // rows i*8 + r0
            const long gr = (long)cu[i >> 1] * 16 + (i & 1) * 8 + r0;
            const float* p = last_equ + gr * 256 + cs * 8;
            f32x4 x = *(const f32x4*)p, y = *(const f32x4*)(p + 4);
            st_a(As, i * 8 + r0, cs, cvt8(x, y));
        }
        lds_barrier();

        // ---- LE = last_equ[parents] @ W_le ----
        f32x4 acc[4][4] = {};
        mfma_tile(As, packLE, 256, wid * 64, 0, acc, lane);

        // cvt to bf16 in-register (same rounding as the old LEp store/load)
        bf16x4 le[4][4];
        #pragma unroll
        for (int rt = 0; rt < 4; ++rt)
            #pragma unroll
            for (int ct = 0; ct < 4; ++ct) {
                le[rt][ct][0] = (__bf16)acc[rt][ct][0];
                le[rt][ct][1] = (__bf16)acc[rt][ct][1];
                le[rt][ct][2] = (__bf16)acc[rt][ct][2];
                le[rt][ct][3] = (__bf16)acc[rt][ct][3];
            }
        lds_barrier();                                // LE ds_reads done

        // ---- stage cur_equ tile ----
        stage_f32<256>(cur_equ, (long)t * 64, As, tid, (long)N_FINE * 16 - 1);
        lds_barrier();

        // ---- CE = cur_equ @ W_ce ----
        #pragma unroll
        for (int rt = 0; rt < 4; ++rt)
            #pragma unroll
            for (int ct = 0; ct < 4; ++ct)
                acc[rt][ct] = f32x4{0.f, 0.f, 0.f, 0.f};
        mfma_tile(As, packCE, 256, wid * 64, 0, acc, lane);

        // ---- product + basis-mean -> equ ----
        #pragma unroll
        for (int rt = 0; rt < 4; ++rt) {
            int n = n0 + rt;
            #pragma unroll
            for (int ct = 0; ct < 4; ++ct) {
                float s = acc[rt][ct][0] * (float)le[rt][ct][0]
                        + acc[rt][ct][1] * (float)le[rt][ct][1]
                        + acc[rt][ct][2] * (float)le[rt][ct][2]
                        + acc[rt][ct][3] * (float)le[rt][ct][3];
                s += __shfl_xor(s, 16, 64);   // basis reduce over lane bit 4
                s += __shfl_xor(s, 32, 64);   // basis reduce over lane bit 5
                if (lane < 16)
                    equ[(size_t)n * 256 + wid * 64 + ct * 16 + lane] =
                        (__bf16)(s * 0.0625f);
            }
        }
        lds_barrier();   // As reads done before next iteration overwrites
    }
}

// ---------------------------------------------------------------------------
// Output: out = [ last_inv[up] | cur_inv | equ ] @ W_mlp  (K=768). R13 form.
// ---------------------------------------------------------------------------
__global__ __launch_bounds__(512) void k_out(
    const __bf16* __restrict__ li_bf, const float* __restrict__ cur_inv,
    const __bf16* __restrict__ equ, const bf16x8* __restrict__ packW,
    const int* __restrict__ up, float* __restrict__ out)
{
    __shared__ __attribute__((aligned(16))) __bf16 As[64 * 256];
    const int tid = threadIdx.x, lane = tid & 63, wid = tid >> 6;
    const int row0 = blockIdx.x * 64;
    const int c0 = wid * 64;
    const int r0 = tid >> 5, cs = tid & 31;
    f32x4 acc[4][4] = {};

    // seg0: gathered last_inv rows (bf16)
    #pragma unroll
    for (int i = 0; i < 4; ++i) {
        int row = r0 + i * 16;
        int gr = row0 + row; if (gr > N_FINE - 1) gr = N_FINE - 1;
        st_a(As, row, cs, *(const bf16x8*)(li_bf + (size_t)up[gr] * 256 + cs * 8));
    }
    lds_barrier();
    mfma_tile(As, packW, 512, c0, 0, acc, lane);
    lds_barrier();

    // seg1: cur_inv (f32)
    stage_f32<512>(cur_inv, row0, As, tid, N_FINE - 1);
    lds_barrier();
    mfma_tile(As, packW, 512, c0, 8, acc, lane);
    lds_barrier();

    // seg2: equ (bf16)
    #pragma unroll
    for (int i = 0; i < 4; ++i) {
        int row = r0 + i * 16;
        int gr = row0 + row; if (gr > N_FINE - 1) gr = N_FINE - 1;
        st_a(As, row, cs, *(const bf16x8*)(equ + (size_t)gr * 256 + cs * 8));
    }
    lds_barrier();
    mfma_tile(As, packW, 512, c0, 16, acc, lane);

    const int g = lane >> 4, r15 = lane & 15;
    #pragma unroll
    for (int rt = 0; rt < 4; ++rt)
        #pragma unroll
        for (int j = 0; j < 4; ++j) {
            int r = row0 + rt * 16 + g * 4 + j;
            if (r < N_FINE)
                #pragma unroll
                for (int ct = 0; ct < 4; ++ct)
                    out[(size_t)r * 512 + c0 + ct * 16 + r15] = acc[rt][ct][j];
        }
}

extern "C" void kernel_launch(void* const* d_in, const int* in_sizes, int n_in,
                              void* d_out, int out_size, void* d_ws, size_t ws_size,
                              hipStream_t stream) {
    const float* last_inv = (const float*)d_in[0];
    const float* cur_inv  = (const float*)d_in[1];
    const float* last_equ = (const float*)d_in[2];
    const float* cur_equ  = (const float*)d_in[3];
    const int*   up       = (const int*)d_in[4];
    const float* W_le     = (const float*)d_in[5];
    const float* W_ce     = (const float*)d_in[6];
    const float* W_mlp    = (const float*)d_in[7];
    float* out = (float*)d_out;

    // workspace carve-up (~35 MB; LEp eliminated)
    char* w = (char*)d_ws;
    __bf16* equ    = (__bf16*)w;  w += (size_t)N_FINE * 256 * 2;        //  25.6 MB
    __bf16* li_bf  = (__bf16*)w;  w += (size_t)N_COARSE * 256 * 2;      //   6.4 MB
    __bf16* packLE = (__bf16*)w;  w += (size_t)256 * 256 * 2;
    __bf16* packCE = (__bf16*)w;  w += (size_t)256 * 256 * 2;
    __bf16* packM  = (__bf16*)w;  w += (size_t)768 * 512 * 2;

    k_prep<<<2048 + 3125, 256, 0, stream>>>(
        W_le, W_ce, W_mlp, last_inv, packLE, packCE, packM, li_bf);

    // fused coarse+fine, persistent: 5 blocks/CU x 256 CUs
    k_fine_equ<<<1280, 256, 0, stream>>>(
        last_equ, cur_equ, (const bf16x8*)packLE, (const bf16x8*)packCE, up, equ);

    k_out<<<(N_FINE + 63) / 64, 512, 0, stream>>>(
        li_bf, cur_inv, equ, (const bf16x8*)packM, up, out);
}

// Round 15
// 526.041 us; speedup vs baseline: 2.3606x; 2.3606x over previous
//
#include <hip/hip_runtime.h>
#include <hip/hip_bf16.h>

#define N_COARSE 12500
#define N_FINE   50000

typedef __bf16 bf16x8 __attribute__((ext_vector_type(8)));
typedef __bf16 bf16x4 __attribute__((ext_vector_type(4)));
typedef float  f32x4  __attribute__((ext_vector_type(4)));

// ---------------------------------------------------------------------------
// Fragment conventions (v_mfma_f32_16x16x32_bf16), HW-verified:
//   a-frag: lane holds A[row = lane&15][k = (lane>>4)*8 + j]
//   b-frag: lane holds B[k = (lane>>4)*8 + j][col = lane&15]
//   d     : lane holds D[row = (lane>>4)*4 + j][col = lane&15]
// ---------------------------------------------------------------------------

__device__ __forceinline__ bf16x8 cvt8(f32x4 x, f32x4 y) {
    bf16x8 r;
    r[0] = (__bf16)x[0]; r[1] = (__bf16)x[1]; r[2] = (__bf16)x[2]; r[3] = (__bf16)x[3];
    r[4] = (__bf16)y[0]; r[5] = (__bf16)y[1]; r[6] = (__bf16)y[2]; r[7] = (__bf16)y[3];
    return r;
}

// Barrier with LDS-only fence (avoids __syncthreads' vmcnt(0) drain).
__device__ __forceinline__ void lds_barrier() {
    asm volatile("s_waitcnt lgkmcnt(0)" ::: "memory");
    __builtin_amdgcn_s_barrier();
}

// ---- LDS A-tile: [64 rows][256 bf16] = 32 KB, XOR-swizzled ----------------
__device__ __forceinline__ int swz(int row, int byte) { return byte ^ ((row & 7) << 4); }
__device__ __forceinline__ void st_a(__bf16* lds, int row, int cs, bf16x8 v) {
    *(bf16x8*)((char*)lds + swz(row, row * 512 + cs * 16)) = v;
}
__device__ __forceinline__ bf16x8 ld_a(const __bf16* lds, int row, int ka) {
    return *(const bf16x8*)((const char*)lds + swz(row, row * 512 + ka * 2));
}

template<int NT>
__device__ __forceinline__ void stage_f32(const float* __restrict__ A, long row0,
                                          __bf16* lds, int tid, long maxrow) {
    const int r0 = tid >> 5, cs = tid & 31;
    constexpr int RPI = NT / 32;
    #pragma unroll
    for (int i = 0; i < 64 / RPI; ++i) {
        int row = r0 + i * RPI;
        long gr = row0 + row; if (gr > maxrow) gr = maxrow;
        const float* p = A + gr * 256 + cs * 8;
        f32x4 x = *(const f32x4*)p, y = *(const f32x4*)(p + 4);
        st_a(lds, row, cs, cvt8(x, y));
    }
}

// 64x64-per-wave MFMA over one 256-wide K segment, A from LDS, B packed global
__device__ __forceinline__ void mfma_tile(const __bf16* lds, const bf16x8* __restrict__ packB,
                                          int N, int c0, int ksb,
                                          f32x4 (&acc)[4][4], int lane) {
    const int g = lane >> 4, r15 = lane & 15;
    #pragma unroll
    for (int ks = 0; ks < 8; ++ks) {
        bf16x8 a[4];
        #pragma unroll
        for (int rt = 0; rt < 4; ++rt)
            a[rt] = ld_a(lds, rt * 16 + r15, ks * 32 + g * 8);
        const size_t kb = (size_t)((ksb + ks) * 4 + g) * N;
        #pragma unroll
        for (int ct = 0; ct < 4; ++ct) {
            bf16x8 b = packB[kb + c0 + ct * 16 + r15];
            #pragma unroll
            for (int rt = 0; rt < 4; ++rt)
                acc[rt][ct] = __builtin_amdgcn_mfma_f32_16x16x32_bf16(a[rt], b, acc[rt][ct], 0, 0, 0);
        }
    }
}

// ---------------------------------------------------------------------------
// Merged prep: pack W_le / W_ce / W_mlp into MFMA b-frag layout + cvt last_inv
// to bf16. Pack layout: dst[((k>>3)*N + n)*8 + (k&7)] = (bf16)W[k*N + n]
// ---------------------------------------------------------------------------
__global__ __launch_bounds__(256) void k_prep(
    const float* __restrict__ W_le, const float* __restrict__ W_ce,
    const float* __restrict__ W_mlp, const float* __restrict__ last_inv,
    __bf16* __restrict__ packLE, __bf16* __restrict__ packCE,
    __bf16* __restrict__ packM, __bf16* __restrict__ li_bf)
{
    const int b = blockIdx.x, tid = threadIdx.x;
    if (b < 256) {                       // W_le pack (256x256)
        int idx = b * 256 + tid, k = idx >> 8, n = idx & 255;
        packLE[(((size_t)(k >> 3) << 8) + n) * 8 + (k & 7)] = (__bf16)W_le[idx];
    } else if (b < 512) {                // W_ce pack (256x256)
        int idx = (b - 256) * 256 + tid, k = idx >> 8, n = idx & 255;
        packCE[(((size_t)(k >> 3) << 8) + n) * 8 + (k & 7)] = (__bf16)W_ce[idx];
    } else if (b < 2048) {               // W_mlp pack (768x512)
        int idx = (b - 512) * 256 + tid, k = idx >> 9, n = idx & 511;
        packM[(((size_t)(k >> 3) << 9) + n) * 8 + (k & 7)] = (__bf16)W_mlp[idx];
    } else {                             // last_inv f32 -> bf16
        int i = (b - 2048) * 256 + tid;
        f32x4 v = ((const f32x4*)last_inv)[i];
        bf16x4 o;
        o[0] = (__bf16)v[0]; o[1] = (__bf16)v[1]; o[2] = (__bf16)v[2]; o[3] = (__bf16)v[3];
        ((bf16x4*)li_bf)[i] = o;
    }
}

// ---------------------------------------------------------------------------
// Coarse: LE = last_equ @ W_last_equ -> LEp (MFMA D-layout, bf16).
// PERSISTENT grid-stride (R13, best measured).
// ---------------------------------------------------------------------------
__global__ __launch_bounds__(256) void k_coarse_equ(
    const float* __restrict__ last_equ, const bf16x8* __restrict__ packW,
    __bf16* __restrict__ LEp)
{
    __shared__ __attribute__((aligned(16))) __bf16 As[64 * 256];
    const int tid = threadIdx.x, lane = tid & 63, wid = tid >> 6;
    for (int t = blockIdx.x; t < N_COARSE * 16 / 64; t += gridDim.x) {
        stage_f32<256>(last_equ, (long)t * 64, As, tid, (long)N_COARSE * 16 - 1);
        lds_barrier();
        f32x4 acc[4][4] = {};
        mfma_tile(As, packW, 256, wid * 64, 0, acc, lane);
        #pragma unroll
        for (int rt = 0; rt < 4; ++rt) {
            int coarse = t * 4 + rt;
            #pragma unroll
            for (int ct = 0; ct < 4; ++ct) {
                int cg = wid * 4 + ct;
                bf16x4 v;
                v[0] = (__bf16)acc[rt][ct][0]; v[1] = (__bf16)acc[rt][ct][1];
                v[2] = (__bf16)acc[rt][ct][2]; v[3] = (__bf16)acc[rt][ct][3];
                *(bf16x4*)(LEp + ((size_t)(coarse * 16 + cg) * 64 + lane) * 4) = v;
            }
        }
        lds_barrier();   // As reads done before next iteration overwrites
    }
}

// ---------------------------------------------------------------------------
// Fine fused, PERSISTENT grid-stride (R13 form, best measured).
// ---------------------------------------------------------------------------
__global__ __launch_bounds__(256) void k_fine_equ(
    const float* __restrict__ cur_equ, const bf16x8* __restrict__ packW,
    const __bf16* __restrict__ LEp, const int* __restrict__ up,
    __bf16* __restrict__ equ)
{
    __shared__ __attribute__((aligned(16))) __bf16 As[64 * 256];
    const int tid = threadIdx.x, lane = tid & 63, wid = tid >> 6;
    for (int t = blockIdx.x; t < N_FINE / 4; t += gridDim.x) {
        const int n0 = t * 4;
        int cu[4];
        #pragma unroll
        for (int rt = 0; rt < 4; ++rt) cu[rt] = up[n0 + rt];   // uniform -> s_load

        stage_f32<256>(cur_equ, (long)t * 64, As, tid, (long)N_FINE * 16 - 1);
        lds_barrier();

        f32x4 acc[4][4] = {};
        mfma_tile(As, packW, 256, wid * 64, 0, acc, lane);

        // LE fragment gathers post-MFMA (VGPRs not live across the GEMM)
        bf16x4 le[4][4];
        #pragma unroll
        for (int rt = 0; rt < 4; ++rt)
            #pragma unroll
            for (int ct = 0; ct < 4; ++ct)
                le[rt][ct] = *(const bf16x4*)(LEp +
                    ((size_t)(cu[rt] * 16 + wid * 4 + ct) * 64 + lane) * 4);

        #pragma unroll
        for (int rt = 0; rt < 4; ++rt) {
            int n = n0 + rt;
            #pragma unroll
            for (int ct = 0; ct < 4; ++ct) {
                float s = acc[rt][ct][0] * (float)le[rt][ct][0]
                        + acc[rt][ct][1] * (float)le[rt][ct][1]
                        + acc[rt][ct][2] * (float)le[rt][ct][2]
                        + acc[rt][ct][3] * (float)le[rt][ct][3];
                s += __shfl_xor(s, 16, 64);   // basis reduce over lane bit 4
                s += __shfl_xor(s, 32, 64);   // basis reduce over lane bit 5
                if (lane < 16)
                    equ[(size_t)n * 256 + wid * 64 + ct * 16 + lane] =
                        (__bf16)(s * 0.0625f);
            }
        }
        lds_barrier();   // As reads done before next iteration overwrites
    }
}

// ---------------------------------------------------------------------------
// Output: out = [ last_inv[up] | cur_inv | equ ] @ W_mlp  (K=768).
// R13 body, now PERSISTENT grid-stride: co-resident blocks desynchronize so
// one block's staging overlaps another's MFMA (the R13-proven convoy fix,
// applied to the last remaining one-shot GEMM kernel).
// ---------------------------------------------------------------------------
__global__ __launch_bounds__(512) void k_out(
    const __bf16* __restrict__ li_bf, const float* __restrict__ cur_inv,
    const __bf16* __restrict__ equ, const bf16x8* __restrict__ packW,
    const int* __restrict__ up, float* __restrict__ out)
{
    __shared__ __attribute__((aligned(16))) __bf16 As[64 * 256];
    const int tid = threadIdx.x, lane = tid & 63, wid = tid >> 6;
    const int c0 = wid * 64;
    const int r0 = tid >> 5, cs = tid & 31;
    const int g = lane >> 4, r15 = lane & 15;

    for (int bt = blockIdx.x; bt < (N_FINE + 63) / 64; bt += gridDim.x) {
        const int row0 = bt * 64;
        f32x4 acc[4][4] = {};

        // seg0: gathered last_inv rows (bf16)
        #pragma unroll
        for (int i = 0; i < 4; ++i) {
            int row = r0 + i * 16;
            int gr = row0 + row; if (gr > N_FINE - 1) gr = N_FINE - 1;
            st_a(As, row, cs, *(const bf16x8*)(li_bf + (size_t)up[gr] * 256 + cs * 8));
        }
        lds_barrier();
        mfma_tile(As, packW, 512, c0, 0, acc, lane);
        lds_barrier();

        // seg1: cur_inv (f32)
        stage_f32<512>(cur_inv, row0, As, tid, N_FINE - 1);
        lds_barrier();
        mfma_tile(As, packW, 512, c0, 8, acc, lane);
        lds_barrier();

        // seg2: equ (bf16)
        #pragma unroll
        for (int i = 0; i < 4; ++i) {
            int row = r0 + i * 16;
            int gr = row0 + row; if (gr > N_FINE - 1) gr = N_FINE - 1;
            st_a(As, row, cs, *(const bf16x8*)(equ + (size_t)gr * 256 + cs * 8));
        }
        lds_barrier();
        mfma_tile(As, packW, 512, c0, 16, acc, lane);

        #pragma unroll
        for (int rt = 0; rt < 4; ++rt)
            #pragma unroll
            for (int j = 0; j < 4; ++j) {
                int r = row0 + rt * 16 + g * 4 + j;
                if (r < N_FINE)
                    #pragma unroll
                    for (int ct = 0; ct < 4; ++ct)
                        out[(size_t)r * 512 + c0 + ct * 16 + r15] = acc[rt][ct][j];
            }
        lds_barrier();   // As reads done before next iteration overwrites
    }
}

extern "C" void kernel_launch(void* const* d_in, const int* in_sizes, int n_in,
                              void* d_out, int out_size, void* d_ws, size_t ws_size,
                              hipStream_t stream) {
    const float* last_inv = (const float*)d_in[0];
    const float* cur_inv  = (const float*)d_in[1];
    const float* last_equ = (const float*)d_in[2];
    const float* cur_equ  = (const float*)d_in[3];
    const int*   up       = (const int*)d_in[4];
    const float* W_le     = (const float*)d_in[5];
    const float* W_ce     = (const float*)d_in[6];
    const float* W_mlp    = (const float*)d_in[7];
    float* out = (float*)d_out;

    // workspace carve-up (~135 MB)
    char* w = (char*)d_ws;
    __bf16* LEp    = (__bf16*)w;  w += (size_t)N_COARSE * 16 * 256 * 2;  // 102.4 MB
    __bf16* equ    = (__bf16*)w;  w += (size_t)N_FINE * 256 * 2;        //  25.6 MB
    __bf16* li_bf  = (__bf16*)w;  w += (size_t)N_COARSE * 256 * 2;      //   6.4 MB
    __bf16* packLE = (__bf16*)w;  w += (size_t)256 * 256 * 2;
    __bf16* packCE = (__bf16*)w;  w += (size_t)256 * 256 * 2;
    __bf16* packM  = (__bf16*)w;  w += (size_t)768 * 512 * 2;

    k_prep<<<2048 + 3125, 256, 0, stream>>>(
        W_le, W_ce, W_mlp, last_inv, packLE, packCE, packM, li_bf);

    // persistent grids (R13-proven): 5 blocks/CU for 256-thread GEMMs
    k_coarse_equ<<<1280, 256, 0, stream>>>(
        last_equ, (const bf16x8*)packLE, LEp);

    k_fine_equ<<<1280, 256, 0, stream>>>(
        cur_equ, (const bf16x8*)packCE, LEp, up, equ);

    // persistent k_out: ~2 blocks/CU (512 threads, 32 KB LDS)
    k_out<<<512, 512, 0, stream>>>(
        li_bf, cur_inv, equ, (const bf16x8*)packM, up, out);
}